// Round 3
// baseline (258.105 us; speedup 1.0000x reference)
//
#include <hip/hip_runtime.h>
#include <hip/hip_bf16.h>

// MHA forward: B=2, T=2048, D=1024, H=16 (head dim 64), causal. fp32 I/O (sniffed).
// R11: fix R10's spill regression. __launch_bounds__(512,4) capped VGPRs at 64
//      (4 blk/CU * 8 waves / 4 SIMD = 8 waves/SIMD -> 512/8 = 64), but R10's
//      key-half-split working set is ~100 VGPR -> ~30 regs spilled to scratch
//      in the inner loop (2x slowdown, all-pipe util halved, 31ms first-touch
//      dispatch; scratch invisible in TCC counters). Relax to (512,2): cap
//      >=128, zero spills. Residency unchanged (LDS 53KB already limits to
//      2 blocks/CU = 4 waves/SIMD; 100 VGPR <= 128 sustains it).
//      Structure otherwise identical to R10 (32 q-rows/wave, key-half split).

typedef __attribute__((ext_vector_type(8))) short bf16x8;   // MFMA A/B frag
typedef __attribute__((ext_vector_type(4))) float f32x4;    // MFMA C/D frag
typedef __attribute__((ext_vector_type(4))) short s16x4;    // 4 bf16 = b64

#define QSCALE 0.18033688011f   // (1/sqrt(64)) * log2(e)

__device__ __forceinline__ int sniff_f32(const void* p) {
    const unsigned short* u = (const unsigned short*)p;
    int c = 0;
    for (int i = 0; i < 256; ++i) {
        int e = (u[i] >> 7) & 0xFF;
        c += (e >= 0x90) ? 1 : 0;
    }
    return c > 8;
}

__device__ __forceinline__ void async_copy16(const void* g, void* l) {
    __builtin_amdgcn_global_load_lds(
        (const __attribute__((address_space(1))) void*)g,
        (__attribute__((address_space(3))) void*)l, 16, 0, 0);
}

// ---------------------------------------------------------------------------
// Convert pass (unchanged)
// ---------------------------------------------------------------------------
struct Cvt { const void* src; __hip_bfloat16* dst; int n; };
struct CvtPack { Cvt a[9]; };

__global__ __launch_bounds__(256) void cvt_bf16(CvtPack pk) {
    const Cvt c = pk.a[blockIdx.y];
    const int f32 = sniff_f32(c.src);
    const int stride = gridDim.x * 256 * 8;
    for (int idx = (blockIdx.x * 256 + threadIdx.x) * 8; idx < c.n; idx += stride) {
        if (f32) {
            const float* s = (const float*)c.src + idx;
            f32x4 a0 = *(const f32x4*)s;
            f32x4 a1 = *(const f32x4*)(s + 4);
            union { __hip_bfloat16 h[8]; bf16x8 v; } u;
#pragma unroll
            for (int e = 0; e < 4; e++) u.h[e]     = (__hip_bfloat16)a0[e];
#pragma unroll
            for (int e = 0; e < 4; e++) u.h[4 + e] = (__hip_bfloat16)a1[e];
            *(bf16x8*)&c.dst[idx] = u.v;
        } else {
            *(bf16x8*)&c.dst[idx] = *(const bf16x8*)((const __hip_bfloat16*)c.src + idx);
        }
    }
}

// ---------------------------------------------------------------------------
// 128x128 GEMM-BT. MODE: 0 = bf16 row-major out, 1 = fp32 row-major out,
// 2 = bf16 out scattered into VT[b][h][d][t] (fused V transpose).
// ---------------------------------------------------------------------------
template <int MODE>
__device__ __forceinline__ void gemm_async_body(
    const __hip_bfloat16* __restrict__ A, const __hip_bfloat16* __restrict__ W,
    const __hip_bfloat16* __restrict__ bias, void* __restrict__ C,
    int M, int N, int K, int bm, int bn, float outscale,
    __hip_bfloat16* sA, __hip_bfloat16* sB)
{
    const int tid  = threadIdx.x;
    const int wave = tid >> 6;
    const int lane = tid & 63;
    const int quad = lane >> 4;
    const int l15  = lane & 15;
    const int wr   = wave >> 1;
    const int wc   = wave & 1;

    const int srow = wave * 16 + (lane >> 2);
    const int scol = (lane & 3) * 8;
    const __hip_bfloat16* gA0 = A + (size_t)(bm + srow) * K + scol;
    const __hip_bfloat16* gB0 = W + (size_t)(bn + srow) * K + scol;
    __hip_bfloat16* sA0 = sA + wave * 512;
    __hip_bfloat16* sB0 = sB + wave * 512;

    f32x4 acc[4][4];
#pragma unroll
    for (int i = 0; i < 4; i++)
#pragma unroll
        for (int j = 0; j < 4; j++) acc[i][j] = (f32x4)0.0f;

    for (int k0 = 0; k0 < K; k0 += 32) {
        __syncthreads();
#pragma unroll
        for (int r = 0; r < 2; r++) {
            async_copy16(gA0 + (size_t)r * 64 * K + k0, sA0 + r * 2048);
            async_copy16(gB0 + (size_t)r * 64 * K + k0, sB0 + r * 2048);
        }
        __syncthreads();

        bf16x8 af[4], bf[4];
#pragma unroll
        for (int i = 0; i < 4; i++)
            af[i] = *(const bf16x8*)&sA[(wr * 64 + i * 16 + l15) * 32 + quad * 8];
#pragma unroll
        for (int j = 0; j < 4; j++)
            bf[j] = *(const bf16x8*)&sB[(wc * 64 + j * 16 + l15) * 32 + quad * 8];
#pragma unroll
        for (int i = 0; i < 4; i++)
#pragma unroll
            for (int j = 0; j < 4; j++)
                acc[i][j] = __builtin_amdgcn_mfma_f32_16x16x32_bf16(af[i], bf[j], acc[i][j], 0, 0, 0);
    }

    float bv[4];
#pragma unroll
    for (int j = 0; j < 4; j++)
        bv[j] = (float)bias[bn + wc * 64 + j * 16 + l15];

    if (MODE == 2) {
        // scatter into VT[((b*16 + h)*64 + dh)*2048 + t], 4 consecutive t per reg
        __hip_bfloat16* VTo = (__hip_bfloat16*)C;
#pragma unroll
        for (int i = 0; i < 4; i++) {
            int tglob = bm + wr * 64 + i * 16 + quad * 4;
            int bb = tglob >> 11, tt = tglob & 2047;
#pragma unroll
            for (int j = 0; j < 4; j++) {
                int d = bn + wc * 64 + j * 16 + l15;
                int hh = d >> 6, dh = d & 63;
                union { __hip_bfloat16 e[4]; s16x4 v; } u;
#pragma unroll
                for (int r = 0; r < 4; r++)
                    u.e[r] = (__hip_bfloat16)(acc[i][j][r] + bv[j]);
                *(s16x4*)&VTo[(((size_t)bb * 16 + hh) * 64 + dh) * 2048 + tt] = u.v;
            }
        }
    } else {
#pragma unroll
        for (int i = 0; i < 4; i++) {
#pragma unroll
            for (int j = 0; j < 4; j++) {
                int col = bn + wc * 64 + j * 16 + l15;
#pragma unroll
                for (int r = 0; r < 4; r++) {
                    int row = bm + wr * 64 + i * 16 + quad * 4 + r;
                    float v = (acc[i][j][r] + bv[j]) * outscale;
                    if (MODE == 1) ((float*)C)[(size_t)row * N + col] = v;
                    else ((__hip_bfloat16*)C)[(size_t)row * N + col] = (__hip_bfloat16)v;
                }
            }
        }
    }
}

__global__ __launch_bounds__(256, 2) void qkv_gemm(
    const __hip_bfloat16* __restrict__ x,
    const __hip_bfloat16* __restrict__ Wq, const __hip_bfloat16* __restrict__ bq, __hip_bfloat16* __restrict__ Q,
    const __hip_bfloat16* __restrict__ Wk, const __hip_bfloat16* __restrict__ bk, __hip_bfloat16* __restrict__ Kb,
    const __hip_bfloat16* __restrict__ Wv, const __hip_bfloat16* __restrict__ bv, __hip_bfloat16* __restrict__ VT,
    int M, int N, int K)
{
    __shared__ __hip_bfloat16 sA[128 * 32];
    __shared__ __hip_bfloat16 sB[128 * 32];
    if (blockIdx.z == 0)
        gemm_async_body<0>(x, Wq, bq, Q, M, N, K, blockIdx.x * 128, blockIdx.y * 128, QSCALE, sA, sB);
    else if (blockIdx.z == 1)
        gemm_async_body<0>(x, Wk, bk, Kb, M, N, K, blockIdx.x * 128, blockIdx.y * 128, 1.0f, sA, sB);
    else
        gemm_async_body<2>(x, Wv, bv, VT, M, N, K, blockIdx.x * 128, blockIdx.y * 128, 1.0f, sA, sB);
}

// ---------------------------------------------------------------------------
// out_gemm 64x128 (unchanged)
// ---------------------------------------------------------------------------
template <bool OF32>
__device__ __forceinline__ void gemm64_body(
    const __hip_bfloat16* __restrict__ A, const __hip_bfloat16* __restrict__ W,
    const __hip_bfloat16* __restrict__ bias, void* __restrict__ C,
    int M, int N, int K, int bm, int bn,
    __hip_bfloat16* sA, __hip_bfloat16* sB)
{
    const int tid  = threadIdx.x;
    const int wave = tid >> 6;
    const int lane = tid & 63;
    const int quad = lane >> 4;
    const int l15  = lane & 15;

    const int srow = wave * 16 + (lane >> 2);
    const int scol = (lane & 3) * 8;
    const __hip_bfloat16* gA0 = A + (size_t)(bm + srow) * K + scol;
    const __hip_bfloat16* gB0 = W + (size_t)(bn + srow) * K + scol;
    __hip_bfloat16* sA0 = sA + wave * 512;
    __hip_bfloat16* sB0 = sB + wave * 512;

    f32x4 acc[4][2];
#pragma unroll
    for (int i = 0; i < 4; i++)
#pragma unroll
        for (int j = 0; j < 2; j++) acc[i][j] = (f32x4)0.0f;

    for (int k0 = 0; k0 < K; k0 += 32) {
        __syncthreads();
        async_copy16(gA0 + k0, sA0);
#pragma unroll
        for (int r = 0; r < 2; r++)
            async_copy16(gB0 + (size_t)r * 64 * K + k0, sB0 + r * 2048);
        __syncthreads();

        bf16x8 af[4], bf[2];
#pragma unroll
        for (int i = 0; i < 4; i++)
            af[i] = *(const bf16x8*)&sA[(i * 16 + l15) * 32 + quad * 8];
#pragma unroll
        for (int j = 0; j < 2; j++)
            bf[j] = *(const bf16x8*)&sB[(wave * 32 + j * 16 + l15) * 32 + quad * 8];
#pragma unroll
        for (int i = 0; i < 4; i++)
#pragma unroll
            for (int j = 0; j < 2; j++)
                acc[i][j] = __builtin_amdgcn_mfma_f32_16x16x32_bf16(af[i], bf[j], acc[i][j], 0, 0, 0);
    }

    float bv[2];
#pragma unroll
    for (int j = 0; j < 2; j++)
        bv[j] = (float)bias[bn + wave * 32 + j * 16 + l15];
#pragma unroll
    for (int i = 0; i < 4; i++) {
#pragma unroll
        for (int j = 0; j < 2; j++) {
            int col = bn + wave * 32 + j * 16 + l15;
#pragma unroll
            for (int r = 0; r < 4; r++) {
                int row = bm + i * 16 + quad * 4 + r;
                float v = acc[i][j][r] + bv[j];
                if (OF32) ((float*)C)[(size_t)row * N + col] = v;
                else      ((__hip_bfloat16*)C)[(size_t)row * N + col] = (__hip_bfloat16)v;
            }
        }
    }
}

__global__ __launch_bounds__(256, 2) void out_gemm(
    const __hip_bfloat16* __restrict__ A, const __hip_bfloat16* __restrict__ W,
    const __hip_bfloat16* __restrict__ bias, const void* __restrict__ origW,
    void* __restrict__ C, int M, int N, int K)
{
    __shared__ __hip_bfloat16 sA[64 * 32];
    __shared__ __hip_bfloat16 sB[128 * 32];
    __shared__ int f32flag;
    if (threadIdx.x == 0) f32flag = sniff_f32(origW);
    __syncthreads();
    if (f32flag)
        gemm64_body<true>(A, W, bias, C, M, N, K, blockIdx.x * 64, blockIdx.y * 128, sA, sB);
    else
        gemm64_body<false>(A, W, bias, C, M, N, K, blockIdx.x * 64, blockIdx.y * 128, sA, sB);
}

// ---------------------------------------------------------------------------
// Flash attention, causal, no-max softmax, S^T formulation.
// R11: 128-row q-tile, 8 waves: half = wave>>2 picks key-half (0-31 / 32-63),
// qg = wave&3 picks 32 q-rows. Each kf/vf LDS read feeds 2 MFMAs (g=0,1).
// Double-buffered K/VT tiles, ONE barrier per iter. Partial O/l combined in
// epilogue via staging LDS. grid (16,16,2); qt = bz ? 15-bx : bx (paired).
// launch_bounds (512,2): VGPR cap >=128 -> no spills (R10's (512,4) capped
// at 64 and spilled ~30 regs).
// ---------------------------------------------------------------------------
#define PADK 68
#define PADP 36
#define KBUF (64 * PADK)

__global__ __launch_bounds__(512, 2) void attn_causal(
    const __hip_bfloat16* __restrict__ Q,
    const __hip_bfloat16* __restrict__ K,
    const __hip_bfloat16* __restrict__ VT,
    __hip_bfloat16* __restrict__ O,
    int T, int D, int H)
{
    __shared__ __hip_bfloat16 smem[4 * KBUF + 8 * 32 * PADP];   // 53.2 KB
    __hip_bfloat16* const sKp  = smem;              // [2][KBUF]
    __hip_bfloat16* const sVTp = smem + 2 * KBUF;   // [2][KBUF]

    const int tid  = threadIdx.x;
    const int wave = tid >> 6;      // 0..7
    const int lane = tid & 63;
    const int quad = lane >> 4;
    const int l15  = lane & 15;

    const int half = wave >> 2;     // key-half of each tile (0: keys 0-31, 1: 32-63)
    const int qg   = wave & 3;      // q-group: 32 rows
    const int koff = half * 32;

    __hip_bfloat16* const sPAw = smem + 4 * KBUF + wave * 32 * PADP;

    const int NT = T >> 7;  // 16 q-tiles of 128
    const int qt = blockIdx.z ? (NT - 1 - (int)blockIdx.x) : (int)blockIdx.x;
    const int h  = blockIdx.y;
    const int b  = blockIdx.z;
    const size_t headoff = (size_t)b * T * D + (size_t)h * 64;
    const size_t vtoff   = ((size_t)b * H + h) * 64 * (size_t)T;

    const int nkt = 2 * qt + 2;
    const int qbase    = qt * 128 + qg * 32;
    const int myrowmax = qbase + 31;

    // Q B-operand fragments in registers (block-lifetime constant)
    bf16x8 qfrag[2][2];
#pragma unroll
    for (int g = 0; g < 2; g++)
#pragma unroll
        for (int kk = 0; kk < 2; kk++)
            qfrag[g][kk] = *(const bf16x8*)&Q[headoff +
                (size_t)(qbase + g * 16 + l15) * D + kk * 32 + quad * 8];

    f32x4 acc_o[2][4];
#pragma unroll
    for (int g = 0; g < 2; g++)
#pragma unroll
        for (int j = 0; j < 4; j++) acc_o[g][j] = (f32x4)0.0f;
    float lacc[2] = {0.f, 0.f};   // per-lane l for q = qbase + g*16 + l15 (partial: quads x key-half)

    const int srow = tid >> 3;        // 0..63: one 16B chunk per thread
    const int sc8  = (tid & 7) * 8;

    // pre-loop: stage kt=0 into buf0, prefetch kt=1
    bf16x8 pk, pv;
    pk = *(const bf16x8*)&K[headoff + (size_t)srow * D + sc8];
    pv = *(const bf16x8*)&VT[vtoff + (size_t)srow * T + sc8];
    *(bf16x8*)&sKp[srow * PADK + sc8]  = pk;
    *(bf16x8*)&sVTp[srow * PADK + sc8] = pv;
    if (nkt > 1) {
        pk = *(const bf16x8*)&K[headoff + (size_t)(64 + srow) * D + sc8];
        pv = *(const bf16x8*)&VT[vtoff + (size_t)srow * T + 64 + sc8];
    }
    __syncthreads();

    for (int kt = 0; kt < nkt; ++kt) {
        const int cur = kt & 1;
        const __hip_bfloat16* sKc  = sKp  + cur * KBUF;
        const __hip_bfloat16* sVTc = sVTp + cur * KBUF;

        // stage next tile into the other buffer (safe: barrier at end of kt-1)
        if (kt + 1 < nkt) {
            *(bf16x8*)&sKp[(1 - cur) * KBUF + srow * PADK + sc8]  = pk;
            *(bf16x8*)&sVTp[(1 - cur) * KBUF + srow * PADK + sc8] = pv;
            if (kt + 2 < nkt) {
                pk = *(const bf16x8*)&K[headoff + (size_t)((kt + 2) * 64 + srow) * D + sc8];
                pv = *(const bf16x8*)&VT[vtoff + (size_t)srow * T + (kt + 2) * 64 + sc8];
            }
        }

        if (kt * 64 + koff <= myrowmax) {   // wave-uniform: this key-half has unmasked keys
            // K fragments for this wave's key-half (A-operand rows = keys)
            bf16x8 kf[2][2];
#pragma unroll
            for (int kk = 0; kk < 2; kk++)
#pragma unroll
                for (int j = 0; j < 2; j++)
                    kf[kk][j] = *(const bf16x8*)&sKc[(koff + j * 16 + l15) * PADK + kk * 32 + quad * 8];

#pragma unroll
            for (int g = 0; g < 2; g++) {
                f32x4 st[2];
#pragma unroll
                for (int j = 0; j < 2; j++) st[j] = (f32x4)0.0f;
                __builtin_amdgcn_s_setprio(1);
#pragma unroll
                for (int kk = 0; kk < 2; kk++)
#pragma unroll
                    for (int j = 0; j < 2; j++)
                        st[j] = __builtin_amdgcn_mfma_f32_16x16x32_bf16(
                            kf[kk][j], qfrag[g][kk], st[j], 0, 0, 0);
                __builtin_amdgcn_s_setprio(0);

                if (kt * 64 + koff + 31 > qbase + g * 16) {   // wave-uniform diag check
                    const int q = qbase + g * 16 + l15;
#pragma unroll
                    for (int j = 0; j < 2; j++) {
                        int keyb = kt * 64 + koff + j * 16 + quad * 4;
#pragma unroll
                        for (int r = 0; r < 4; r++)
                            if (keyb + r > q) st[j][r] = -1e30f;
                    }
                }

#pragma unroll
                for (int j = 0; j < 2; j++) {
                    union { __hip_bfloat16 e[4]; s16x4 v; } u;
#pragma unroll
                    for (int r = 0; r < 4; r++) {
                        float p = exp2f(st[j][r]);
                        lacc[g] += p;
                        u.e[r] = (__hip_bfloat16)p;
                    }
                    // 4 contiguous local keys at row q: one b64 write
                    *(s16x4*)&sPAw[(g * 16 + l15) * PADP + j * 16 + quad * 4] = u.v;
                }
            }

            // V fragments (B-operand: contraction over this wave's 32 keys)
            bf16x8 vf[4];
#pragma unroll
            for (int j = 0; j < 4; j++)
                vf[j] = *(const bf16x8*)&sVTc[(j * 16 + l15) * PADK + koff + quad * 8];

            // sPA wave-local: lgkmcnt orders write->read, no barrier.
            __builtin_amdgcn_s_setprio(1);
#pragma unroll
            for (int g = 0; g < 2; g++) {
                bf16x8 a = *(const bf16x8*)&sPAw[(g * 16 + l15) * PADP + quad * 8];
#pragma unroll
                for (int j = 0; j < 4; j++)
                    acc_o[g][j] = __builtin_amdgcn_mfma_f32_16x16x32_bf16(
                        a, vf[j], acc_o[g][j], 0, 0, 0);
            }
            __builtin_amdgcn_s_setprio(0);
        }

        __syncthreads();   // single barrier per iter
    }

    // reduce l over quads (each lane: q = qbase + g*16 + l15, partial over its quad's keys)
#pragma unroll
    for (int g = 0; g < 2; g++) {
        lacc[g] += __shfl_xor(lacc[g], 16, 64);
        lacc[g] += __shfl_xor(lacc[g], 32, 64);
    }

    // cross-key-half combine via staging LDS (dead after final barrier above)
    float* const sc  = (float*)smem;          // 32 KB: [qg][g*4+j][lane] f32x4
    float* const lsc = (float*)smem + 8192;   // 512 B: [qg][g][l15]
    if (half == 1) {
#pragma unroll
        for (int g = 0; g < 2; g++)
#pragma unroll
            for (int j = 0; j < 4; j++)
                *(f32x4*)&sc[((qg * 8 + g * 4 + j) * 64 + lane) * 4] = acc_o[g][j];
        if (quad == 0) {
            lsc[(qg * 2 + 0) * 16 + l15] = lacc[0];
            lsc[(qg * 2 + 1) * 16 + l15] = lacc[1];
        }
    }
    __syncthreads();
    if (half == 0) {
#pragma unroll
        for (int g = 0; g < 2; g++) {
            lacc[g] += lsc[(qg * 2 + g) * 16 + l15];
#pragma unroll
            for (int j = 0; j < 4; j++) {
                f32x4 t = *(const f32x4*)&sc[((qg * 8 + g * 4 + j) * 64 + lane) * 4];
                acc_o[g][j] += t;
            }
        }
        // acc_o rows are q = quad*4+r: fetch l from lane quad*4+r via shfl
#pragma unroll
        for (int g = 0; g < 2; g++)
#pragma unroll
            for (int r = 0; r < 4; r++) {
                float linv = 1.0f / __shfl(lacc[g], quad * 4 + r, 64);
                int row = qbase + g * 16 + quad * 4 + r;
#pragma unroll
                for (int j = 0; j < 4; j++) {
                    int col = j * 16 + l15;
                    O[headoff + (size_t)row * D + col] = (__hip_bfloat16)(acc_o[g][j][r] * linv);
                }
            }
    }
}

// ---------------------------------------------------------------------------
extern "C" void kernel_launch(void* const* d_in, const int* in_sizes, int n_in,
                              void* d_out, int out_size, void* d_ws, size_t ws_size,
                              hipStream_t stream) {
    const int Bb = 2, T = 2048, D = 1024, H = 16;
    const int M = Bb * T;   // 4096

    __hip_bfloat16* w = (__hip_bfloat16*)d_ws;
    __hip_bfloat16* Q   = w;
    __hip_bfloat16* Kb  = Q   + (size_t)M * D;
    __hip_bfloat16* VT  = Kb  + (size_t)M * D;
    __hip_bfloat16* ctx = VT  + (size_t)M * D;
    __hip_bfloat16* xb  = ctx + (size_t)M * D;
    __hip_bfloat16* Wqb = xb  + (size_t)M * D;
    __hip_bfloat16* Wkb = Wqb + (size_t)D * D;
    __hip_bfloat16* Wvb = Wkb + (size_t)D * D;
    __hip_bfloat16* Wob = Wvb + (size_t)D * D;
    __hip_bfloat16* bqb = Wob + (size_t)D * D;
    __hip_bfloat16* bkb = bqb + D;
    __hip_bfloat16* bvb = bkb + D;
    __hip_bfloat16* bob = bvb + D;

    CvtPack pk;
    pk.a[0] = { d_in[0], xb,  M * D };
    pk.a[1] = { d_in[1], Wqb, D * D };
    pk.a[2] = { d_in[2], bqb, D };
    pk.a[3] = { d_in[3], Wkb, D * D };
    pk.a[4] = { d_in[4], bkb, D };
    pk.a[5] = { d_in[5], Wvb, D * D };
    pk.a[6] = { d_in[6], bvb, D };
    pk.a[7] = { d_in[7], Wob, D * D };
    pk.a[8] = { d_in[8], bob, D };

    cvt_bf16<<<dim3(512, 9), 256, 0, stream>>>(pk);
    qkv_gemm<<<dim3(M / 128, D / 128, 3), 256, 0, stream>>>(
        xb, Wqb, bqb, Q, Wkb, bkb, Kb, Wvb, bvb, VT, M, D, D);
    attn_causal<<<dim3(T / 128, H, Bb), 512, 0, stream>>>(Q, Kb, VT, ctx, T, D, H);
    out_gemm<<<dim3(M / 64, D / 128), 256, 0, stream>>>(
        ctx, Wob, bob, d_in[7], d_out, M, D, D);
}

// Round 4
// 211.096 us; speedup vs baseline: 1.2227x; 1.2227x over previous
//
#include <hip/hip_runtime.h>
#include <hip/hip_bf16.h>

// MHA forward: B=2, T=2048, D=1024, H=16 (head dim 64), causal. fp32 I/O (sniffed).
// R12: (1) REVERT attn_causal to the R9 version verbatim (proven 46.5us;
//      R10/R11's key-half split was intrinsically 2x slower — VGPR stayed 64
//      and perf identical under relaxed launch bounds, falsifying the spill
//      theory; structure abandoned).
//      (2) qkv_gemm MODE 2 (fused V-transpose) output path: was 8B scattered
//      stores at 4KB stride (~8x write amplification on VT). Now stage the
//      128x128 tile in LDS as [d][t] (stride 136) and write VT coalesced
//      (16B/lane, 256B contiguous per d-row). LDS 16->34KB (no occupancy
//      change: grid is 3 blocks/CU, 34KB allows 4).

typedef __attribute__((ext_vector_type(8))) short bf16x8;   // MFMA A/B frag
typedef __attribute__((ext_vector_type(4))) float f32x4;    // MFMA C/D frag
typedef __attribute__((ext_vector_type(4))) short s16x4;    // 4 bf16 = b64

#define QSCALE 0.18033688011f   // (1/sqrt(64)) * log2(e)

__device__ __forceinline__ int sniff_f32(const void* p) {
    const unsigned short* u = (const unsigned short*)p;
    int c = 0;
    for (int i = 0; i < 256; ++i) {
        int e = (u[i] >> 7) & 0xFF;
        c += (e >= 0x90) ? 1 : 0;
    }
    return c > 8;
}

__device__ __forceinline__ void async_copy16(const void* g, void* l) {
    __builtin_amdgcn_global_load_lds(
        (const __attribute__((address_space(1))) void*)g,
        (__attribute__((address_space(3))) void*)l, 16, 0, 0);
}

// ---------------------------------------------------------------------------
// Convert pass (unchanged)
// ---------------------------------------------------------------------------
struct Cvt { const void* src; __hip_bfloat16* dst; int n; };
struct CvtPack { Cvt a[9]; };

__global__ __launch_bounds__(256) void cvt_bf16(CvtPack pk) {
    const Cvt c = pk.a[blockIdx.y];
    const int f32 = sniff_f32(c.src);
    const int stride = gridDim.x * 256 * 8;
    for (int idx = (blockIdx.x * 256 + threadIdx.x) * 8; idx < c.n; idx += stride) {
        if (f32) {
            const float* s = (const float*)c.src + idx;
            f32x4 a0 = *(const f32x4*)s;
            f32x4 a1 = *(const f32x4*)(s + 4);
            union { __hip_bfloat16 h[8]; bf16x8 v; } u;
#pragma unroll
            for (int e = 0; e < 4; e++) u.h[e]     = (__hip_bfloat16)a0[e];
#pragma unroll
            for (int e = 0; e < 4; e++) u.h[4 + e] = (__hip_bfloat16)a1[e];
            *(bf16x8*)&c.dst[idx] = u.v;
        } else {
            *(bf16x8*)&c.dst[idx] = *(const bf16x8*)((const __hip_bfloat16*)c.src + idx);
        }
    }
}

// ---------------------------------------------------------------------------
// 128x128 GEMM-BT. MODE: 0 = bf16 row-major out, 1 = fp32 row-major out,
// 2 = bf16 out into VT[b][h][d][t] via LDS-staged coalesced writes.
// ---------------------------------------------------------------------------
template <int MODE>
__device__ __forceinline__ void gemm_async_body(
    const __hip_bfloat16* __restrict__ A, const __hip_bfloat16* __restrict__ W,
    const __hip_bfloat16* __restrict__ bias, void* __restrict__ C,
    int M, int N, int K, int bm, int bn, float outscale,
    __hip_bfloat16* sA, __hip_bfloat16* sB)
{
    const int tid  = threadIdx.x;
    const int wave = tid >> 6;
    const int lane = tid & 63;
    const int quad = lane >> 4;
    const int l15  = lane & 15;
    const int wr   = wave >> 1;
    const int wc   = wave & 1;

    const int srow = wave * 16 + (lane >> 2);
    const int scol = (lane & 3) * 8;
    const __hip_bfloat16* gA0 = A + (size_t)(bm + srow) * K + scol;
    const __hip_bfloat16* gB0 = W + (size_t)(bn + srow) * K + scol;
    __hip_bfloat16* sA0 = sA + wave * 512;
    __hip_bfloat16* sB0 = sB + wave * 512;

    f32x4 acc[4][4];
#pragma unroll
    for (int i = 0; i < 4; i++)
#pragma unroll
        for (int j = 0; j < 4; j++) acc[i][j] = (f32x4)0.0f;

    for (int k0 = 0; k0 < K; k0 += 32) {
        __syncthreads();
#pragma unroll
        for (int r = 0; r < 2; r++) {
            async_copy16(gA0 + (size_t)r * 64 * K + k0, sA0 + r * 2048);
            async_copy16(gB0 + (size_t)r * 64 * K + k0, sB0 + r * 2048);
        }
        __syncthreads();

        bf16x8 af[4], bf[4];
#pragma unroll
        for (int i = 0; i < 4; i++)
            af[i] = *(const bf16x8*)&sA[(wr * 64 + i * 16 + l15) * 32 + quad * 8];
#pragma unroll
        for (int j = 0; j < 4; j++)
            bf[j] = *(const bf16x8*)&sB[(wc * 64 + j * 16 + l15) * 32 + quad * 8];
#pragma unroll
        for (int i = 0; i < 4; i++)
#pragma unroll
            for (int j = 0; j < 4; j++)
                acc[i][j] = __builtin_amdgcn_mfma_f32_16x16x32_bf16(af[i], bf[j], acc[i][j], 0, 0, 0);
    }

    float bv[4];
#pragma unroll
    for (int j = 0; j < 4; j++)
        bv[j] = (float)bias[bn + wc * 64 + j * 16 + l15];

    if (MODE == 2) {
        // Stage tile as sOut[d_local][t_local] (stride 136: 272B, 16B-aligned
        // rows), then write VT with coalesced 16B stores (256B runs per d-row).
        __hip_bfloat16* sOut = sA;           // reuse staging LDS (34KB)
        __syncthreads();                     // all waves done reading sA/sB
#pragma unroll
        for (int i = 0; i < 4; i++) {
            int tl = wr * 64 + i * 16 + quad * 4;
#pragma unroll
            for (int j = 0; j < 4; j++) {
                int dl = wc * 64 + j * 16 + l15;
                union { __hip_bfloat16 e[4]; s16x4 v; } u;
#pragma unroll
                for (int r = 0; r < 4; r++)
                    u.e[r] = (__hip_bfloat16)(acc[i][j][r] + bv[j]);
                *(s16x4*)&sOut[dl * 136 + tl] = u.v;
            }
        }
        __syncthreads();
        __hip_bfloat16* VTo = (__hip_bfloat16*)C;
        const int bb = bm >> 11, tt0 = bm & 2047;
#pragma unroll
        for (int g8 = 0; g8 < 8; g8++) {
            int idx = g8 * 256 + tid;
            int dl  = idx >> 4;
            int tc  = (idx & 15) * 8;
            int dg  = bn + dl;
            bf16x8 v = *(const bf16x8*)&sOut[dl * 136 + tc];
            *(bf16x8*)&VTo[(((size_t)bb * 16 + (dg >> 6)) * 64 + (dg & 63)) * 2048 + tt0 + tc] = v;
        }
    } else {
#pragma unroll
        for (int i = 0; i < 4; i++) {
#pragma unroll
            for (int j = 0; j < 4; j++) {
                int col = bn + wc * 64 + j * 16 + l15;
#pragma unroll
                for (int r = 0; r < 4; r++) {
                    int row = bm + wr * 64 + i * 16 + quad * 4 + r;
                    float v = (acc[i][j][r] + bv[j]) * outscale;
                    if (MODE == 1) ((float*)C)[(size_t)row * N + col] = v;
                    else ((__hip_bfloat16*)C)[(size_t)row * N + col] = (__hip_bfloat16)v;
                }
            }
        }
    }
}

__global__ __launch_bounds__(256, 2) void qkv_gemm(
    const __hip_bfloat16* __restrict__ x,
    const __hip_bfloat16* __restrict__ Wq, const __hip_bfloat16* __restrict__ bq, __hip_bfloat16* __restrict__ Q,
    const __hip_bfloat16* __restrict__ Wk, const __hip_bfloat16* __restrict__ bk, __hip_bfloat16* __restrict__ Kb,
    const __hip_bfloat16* __restrict__ Wv, const __hip_bfloat16* __restrict__ bv, __hip_bfloat16* __restrict__ VT,
    int M, int N, int K)
{
    __shared__ __hip_bfloat16 smem[128 * 136];   // sA[128*32] | sB[128*32] in K-loop; sOut after
    __hip_bfloat16* sA = smem;
    __hip_bfloat16* sB = smem + 128 * 32;
    if (blockIdx.z == 0)
        gemm_async_body<0>(x, Wq, bq, Q, M, N, K, blockIdx.x * 128, blockIdx.y * 128, QSCALE, sA, sB);
    else if (blockIdx.z == 1)
        gemm_async_body<0>(x, Wk, bk, Kb, M, N, K, blockIdx.x * 128, blockIdx.y * 128, 1.0f, sA, sB);
    else
        gemm_async_body<2>(x, Wv, bv, VT, M, N, K, blockIdx.x * 128, blockIdx.y * 128, 1.0f, sA, sB);
}

// ---------------------------------------------------------------------------
// out_gemm 64x128 (unchanged)
// ---------------------------------------------------------------------------
template <bool OF32>
__device__ __forceinline__ void gemm64_body(
    const __hip_bfloat16* __restrict__ A, const __hip_bfloat16* __restrict__ W,
    const __hip_bfloat16* __restrict__ bias, void* __restrict__ C,
    int M, int N, int K, int bm, int bn,
    __hip_bfloat16* sA, __hip_bfloat16* sB)
{
    const int tid  = threadIdx.x;
    const int wave = tid >> 6;
    const int lane = tid & 63;
    const int quad = lane >> 4;
    const int l15  = lane & 15;

    const int srow = wave * 16 + (lane >> 2);
    const int scol = (lane & 3) * 8;
    const __hip_bfloat16* gA0 = A + (size_t)(bm + srow) * K + scol;
    const __hip_bfloat16* gB0 = W + (size_t)(bn + srow) * K + scol;
    __hip_bfloat16* sA0 = sA + wave * 512;
    __hip_bfloat16* sB0 = sB + wave * 512;

    f32x4 acc[4][2];
#pragma unroll
    for (int i = 0; i < 4; i++)
#pragma unroll
        for (int j = 0; j < 2; j++) acc[i][j] = (f32x4)0.0f;

    for (int k0 = 0; k0 < K; k0 += 32) {
        __syncthreads();
        async_copy16(gA0 + k0, sA0);
#pragma unroll
        for (int r = 0; r < 2; r++)
            async_copy16(gB0 + (size_t)r * 64 * K + k0, sB0 + r * 2048);
        __syncthreads();

        bf16x8 af[4], bf[2];
#pragma unroll
        for (int i = 0; i < 4; i++)
            af[i] = *(const bf16x8*)&sA[(i * 16 + l15) * 32 + quad * 8];
#pragma unroll
        for (int j = 0; j < 2; j++)
            bf[j] = *(const bf16x8*)&sB[(wave * 32 + j * 16 + l15) * 32 + quad * 8];
#pragma unroll
        for (int i = 0; i < 4; i++)
#pragma unroll
            for (int j = 0; j < 2; j++)
                acc[i][j] = __builtin_amdgcn_mfma_f32_16x16x32_bf16(af[i], bf[j], acc[i][j], 0, 0, 0);
    }

    float bv[2];
#pragma unroll
    for (int j = 0; j < 2; j++)
        bv[j] = (float)bias[bn + wave * 32 + j * 16 + l15];
#pragma unroll
    for (int i = 0; i < 4; i++) {
#pragma unroll
        for (int j = 0; j < 2; j++) {
            int col = bn + wave * 32 + j * 16 + l15;
#pragma unroll
            for (int r = 0; r < 4; r++) {
                int row = bm + i * 16 + quad * 4 + r;
                float v = acc[i][j][r] + bv[j];
                if (OF32) ((float*)C)[(size_t)row * N + col] = v;
                else      ((__hip_bfloat16*)C)[(size_t)row * N + col] = (__hip_bfloat16)v;
            }
        }
    }
}

__global__ __launch_bounds__(256, 2) void out_gemm(
    const __hip_bfloat16* __restrict__ A, const __hip_bfloat16* __restrict__ W,
    const __hip_bfloat16* __restrict__ bias, const void* __restrict__ origW,
    void* __restrict__ C, int M, int N, int K)
{
    __shared__ __hip_bfloat16 sA[64 * 32];
    __shared__ __hip_bfloat16 sB[128 * 32];
    __shared__ int f32flag;
    if (threadIdx.x == 0) f32flag = sniff_f32(origW);
    __syncthreads();
    if (f32flag)
        gemm64_body<true>(A, W, bias, C, M, N, K, blockIdx.x * 64, blockIdx.y * 128, sA, sB);
    else
        gemm64_body<false>(A, W, bias, C, M, N, K, blockIdx.x * 64, blockIdx.y * 128, sA, sB);
}

// ---------------------------------------------------------------------------
// Flash attention, causal, no-max softmax, S^T formulation.  (R9 verbatim)
// 128-row q-tile, EIGHT waves x 16 q-rows. Double-buffered K/VT tiles,
// ONE barrier per iter. S^T = MFMA(A=K-rows, B=Q-rows): C col=l15=q,
// row=quad*4+r=key -> P values are 4 keys contiguous per (j): b64 sP writes.
// l is scalar/lane (q=l15); epilogue shuffles l to the C-layout rows.
// grid (16,16,2); qt = bz ? 15-bx : bx. 2 blocks/CU (104KB LDS) = 16 waves/CU.
// ---------------------------------------------------------------------------
#define PAD 68

__global__ __launch_bounds__(512, 4) void attn_causal(
    const __hip_bfloat16* __restrict__ Q,
    const __hip_bfloat16* __restrict__ K,
    const __hip_bfloat16* __restrict__ VT,
    __hip_bfloat16* __restrict__ O,
    int T, int D, int H)
{
    __shared__ __hip_bfloat16 sK[2][64 * PAD];
    __shared__ __hip_bfloat16 sVT[2][64 * PAD];
    __shared__ __hip_bfloat16 sPA[8][16 * PAD];   // per-wave P in A-layout

    const int tid  = threadIdx.x;
    const int wave = tid >> 6;      // 0..7
    const int lane = tid & 63;
    const int quad = lane >> 4;
    const int l15  = lane & 15;

    const int NT = T >> 7;  // 16 q-tiles of 128
    const int qt = blockIdx.z ? (NT - 1 - (int)blockIdx.x) : (int)blockIdx.x;
    const int h  = blockIdx.y;
    const int b  = blockIdx.z;
    const size_t headoff = (size_t)b * T * D + (size_t)h * 64;
    const size_t vtoff   = ((size_t)b * H + h) * 64 * (size_t)T;

    const int nkt = 2 * qt + 2;
    const int qbase    = qt * 128 + wave * 16;
    const int myrowmax = qbase + 15;

    // Q B-operand fragments in registers (block-lifetime constant)
    bf16x8 qfrag[2];
#pragma unroll
    for (int kk = 0; kk < 2; kk++)
        qfrag[kk] = *(const bf16x8*)&Q[headoff +
            (size_t)(qbase + l15) * D + kk * 32 + quad * 8];

    f32x4 acc_o[4];
#pragma unroll
    for (int j = 0; j < 4; j++) acc_o[j] = (f32x4)0.0f;
    float lacc = 0.f;   // per-lane l for q = qbase + l15 (partial over quads)

    const int srow = tid >> 3;        // 0..63: one 16B chunk per thread
    const int sc8  = (tid & 7) * 8;

    // pre-loop: stage kt=0 into buf0, prefetch kt=1
    bf16x8 pk, pv;
    pk = *(const bf16x8*)&K[headoff + (size_t)srow * D + sc8];
    pv = *(const bf16x8*)&VT[vtoff + (size_t)srow * T + sc8];
    *(bf16x8*)&sK[0][srow * PAD + sc8]  = pk;
    *(bf16x8*)&sVT[0][srow * PAD + sc8] = pv;
    if (nkt > 1) {
        pk = *(const bf16x8*)&K[headoff + (size_t)(64 + srow) * D + sc8];
        pv = *(const bf16x8*)&VT[vtoff + (size_t)srow * T + 64 + sc8];
    }
    __syncthreads();

    for (int kt = 0; kt < nkt; ++kt) {
        const int cur = kt & 1;

        // stage next tile into the other buffer (safe: barrier at end of kt-1
        // means all waves finished reading it in kt-1)
        if (kt + 1 < nkt) {
            *(bf16x8*)&sK[1 - cur][srow * PAD + sc8]  = pk;
            *(bf16x8*)&sVT[1 - cur][srow * PAD + sc8] = pv;
            if (kt + 2 < nkt) {
                pk = *(const bf16x8*)&K[headoff + (size_t)((kt + 2) * 64 + srow) * D + sc8];
                pv = *(const bf16x8*)&VT[vtoff + (size_t)srow * T + (kt + 2) * 64 + sc8];
            }
        }

        if (kt * 64 <= myrowmax) {
            // K/V fragments (A-operand = rows of K / rows of VT)
            bf16x8 kfrag[2][4], vfrag[2][4];
#pragma unroll
            for (int kk = 0; kk < 2; kk++)
#pragma unroll
                for (int j = 0; j < 4; j++) {
                    kfrag[kk][j] = *(const bf16x8*)&sK[cur][(j * 16 + l15) * PAD + kk * 32 + quad * 8];
                    vfrag[kk][j] = *(const bf16x8*)&sVT[cur][(j * 16 + l15) * PAD + kk * 32 + quad * 8];
                }

            f32x4 st[4];
#pragma unroll
            for (int j = 0; j < 4; j++) st[j] = (f32x4)0.0f;
            __builtin_amdgcn_s_setprio(1);
#pragma unroll
            for (int kk = 0; kk < 2; kk++)
#pragma unroll
                for (int j = 0; j < 4; j++)
                    st[j] = __builtin_amdgcn_mfma_f32_16x16x32_bf16(
                        kfrag[kk][j], qfrag[kk], st[j], 0, 0, 0);
            __builtin_amdgcn_s_setprio(0);

            if (kt * 64 + 63 > qbase) {   // wave-uniform mask check (diag tile)
                const int q = qbase + l15;
#pragma unroll
                for (int j = 0; j < 4; j++) {
                    int keyb = kt * 64 + j * 16 + quad * 4;
#pragma unroll
                    for (int r = 0; r < 4; r++)
                        if (keyb + r > q) st[j][r] = -1e30f;
                }
            }

#pragma unroll
            for (int j = 0; j < 4; j++) {
                union { __hip_bfloat16 e[4]; s16x4 v; } u;
#pragma unroll
                for (int r = 0; r < 4; r++) {
                    float p = exp2f(st[j][r]);
                    lacc += p;
                    u.e[r] = (__hip_bfloat16)p;
                }
                // 4 contiguous keys at row q=l15: one b64 write
                *(s16x4*)&sPA[wave][l15 * PAD + j * 16 + quad * 4] = u.v;
            }
            // sPA wave-local: lgkmcnt orders write->read, no barrier.
            __builtin_amdgcn_s_setprio(1);
#pragma unroll
            for (int kk = 0; kk < 2; kk++) {
                bf16x8 a = *(const bf16x8*)&sPA[wave][l15 * PAD + kk * 32 + quad * 8];
#pragma unroll
                for (int j = 0; j < 4; j++)
                    acc_o[j] = __builtin_amdgcn_mfma_f32_16x16x32_bf16(
                        a, vfrag[kk][j], acc_o[j], 0, 0, 0);
            }
            __builtin_amdgcn_s_setprio(0);
        }

        __syncthreads();   // single barrier per iter
    }

    // l lives per-lane for q=l15 (partial over quads): reduce across quads
    lacc += __shfl_xor(lacc, 16, 64);
    lacc += __shfl_xor(lacc, 32, 64);

    // acc_o rows are q = quad*4+r: fetch l from lane quad*4+r via shfl
#pragma unroll
    for (int r = 0; r < 4; r++) {
        float linv = 1.0f / __shfl(lacc, quad * 4 + r, 64);
        int row = qbase + quad * 4 + r;
#pragma unroll
        for (int j = 0; j < 4; j++) {
            int col = j * 16 + l15;
            O[headoff + (size_t)row * D + col] = (__hip_bfloat16)(acc_o[j][r] * linv);
        }
    }
}

// ---------------------------------------------------------------------------
extern "C" void kernel_launch(void* const* d_in, const int* in_sizes, int n_in,
                              void* d_out, int out_size, void* d_ws, size_t ws_size,
                              hipStream_t stream) {
    const int Bb = 2, T = 2048, D = 1024, H = 16;
    const int M = Bb * T;   // 4096

    __hip_bfloat16* w = (__hip_bfloat16*)d_ws;
    __hip_bfloat16* Q   = w;
    __hip_bfloat16* Kb  = Q   + (size_t)M * D;
    __hip_bfloat16* VT  = Kb  + (size_t)M * D;
    __hip_bfloat16* ctx = VT  + (size_t)M * D;
    __hip_bfloat16* xb  = ctx + (size_t)M * D;
    __hip_bfloat16* Wqb = xb  + (size_t)M * D;
    __hip_bfloat16* Wkb = Wqb + (size_t)D * D;
    __hip_bfloat16* Wvb = Wkb + (size_t)D * D;
    __hip_bfloat16* Wob = Wvb + (size_t)D * D;
    __hip_bfloat16* bqb = Wob + (size_t)D * D;
    __hip_bfloat16* bkb = bqb + D;
    __hip_bfloat16* bvb = bkb + D;
    __hip_bfloat16* bob = bvb + D;

    CvtPack pk;
    pk.a[0] = { d_in[0], xb,  M * D };
    pk.a[1] = { d_in[1], Wqb, D * D };
    pk.a[2] = { d_in[2], bqb, D };
    pk.a[3] = { d_in[3], Wkb, D * D };
    pk.a[4] = { d_in[4], bkb, D };
    pk.a[5] = { d_in[5], Wvb, D * D };
    pk.a[6] = { d_in[6], bvb, D };
    pk.a[7] = { d_in[7], Wob, D * D };
    pk.a[8] = { d_in[8], bob, D };

    cvt_bf16<<<dim3(512, 9), 256, 0, stream>>>(pk);
    qkv_gemm<<<dim3(M / 128, D / 128, 3), 256, 0, stream>>>(
        xb, Wqb, bqb, Q, Wkb, bkb, Kb, Wvb, bvb, VT, M, D, D);
    attn_causal<<<dim3(T / 128, H, Bb), 512, 0, stream>>>(Q, Kb, VT, ctx, T, D, H);
    out_gemm<<<dim3(M / 64, D / 128), 256, 0, stream>>>(
        ctx, Wob, bob, d_in[7], d_out, M, D, D);
}

// Round 5
// 206.784 us; speedup vs baseline: 1.2482x; 1.0209x over previous
//
#include <hip/hip_runtime.h>
#include <hip/hip_bf16.h>

// MHA forward: B=2, T=2048, D=1024, H=16 (head dim 64), causal. fp32 I/O (sniffed).
// R13: GEMM pipeline fix (T3-min recipe). Both GEMM bodies previously did
//      {issue global_load_lds -> __syncthreads()} per K-step: the compiler
//      emits s_waitcnt vmcnt(0) before s_barrier, exposing full HBM/L2 load
//      latency every one of 32 K-steps with only 2-3 blocks/CU to hide it.
//      Now: double-buffered LDS staging, prefetch tile t+1 BEFORE computing
//      tile t, counted vmcnt(4)/(3) via inline asm (never 0 in-loop), raw
//      s_barrier (no compiler drain); vmcnt(0) only on the peeled last iter.
//      attn_causal: R9/R12 verbatim (proven 46.7us). cvt unchanged.

typedef __attribute__((ext_vector_type(8))) short bf16x8;   // MFMA A/B frag
typedef __attribute__((ext_vector_type(4))) float f32x4;    // MFMA C/D frag
typedef __attribute__((ext_vector_type(4))) short s16x4;    // 4 bf16 = b64

#define QSCALE 0.18033688011f   // (1/sqrt(64)) * log2(e)

__device__ __forceinline__ int sniff_f32(const void* p) {
    const unsigned short* u = (const unsigned short*)p;
    int c = 0;
    for (int i = 0; i < 256; ++i) {
        int e = (u[i] >> 7) & 0xFF;
        c += (e >= 0x90) ? 1 : 0;
    }
    return c > 8;
}

__device__ __forceinline__ void async_copy16(const void* g, void* l) {
    __builtin_amdgcn_global_load_lds(
        (const __attribute__((address_space(1))) void*)g,
        (__attribute__((address_space(3))) void*)l, 16, 0, 0);
}

// ---------------------------------------------------------------------------
// Convert pass (unchanged)
// ---------------------------------------------------------------------------
struct Cvt { const void* src; __hip_bfloat16* dst; int n; };
struct CvtPack { Cvt a[9]; };

__global__ __launch_bounds__(256) void cvt_bf16(CvtPack pk) {
    const Cvt c = pk.a[blockIdx.y];
    const int f32 = sniff_f32(c.src);
    const int stride = gridDim.x * 256 * 8;
    for (int idx = (blockIdx.x * 256 + threadIdx.x) * 8; idx < c.n; idx += stride) {
        if (f32) {
            const float* s = (const float*)c.src + idx;
            f32x4 a0 = *(const f32x4*)s;
            f32x4 a1 = *(const f32x4*)(s + 4);
            union { __hip_bfloat16 h[8]; bf16x8 v; } u;
#pragma unroll
            for (int e = 0; e < 4; e++) u.h[e]     = (__hip_bfloat16)a0[e];
#pragma unroll
            for (int e = 0; e < 4; e++) u.h[4 + e] = (__hip_bfloat16)a1[e];
            *(bf16x8*)&c.dst[idx] = u.v;
        } else {
            *(bf16x8*)&c.dst[idx] = *(const bf16x8*)((const __hip_bfloat16*)c.src + idx);
        }
    }
}

// ---------------------------------------------------------------------------
// 128x128 GEMM-BT, 2-phase prefetch. MODE: 0 = bf16 row-major out,
// 1 = fp32 row-major out, 2 = bf16 out into VT[b][h][d][t] via LDS-staged
// coalesced writes. smem layout in K-loop: [buf][sA 4096 | sB 4096] (32KB);
// MODE2 epilogue reuses smem as sOut[128][136] (34.8KB alloc).
// ---------------------------------------------------------------------------
template <int MODE>
__device__ __forceinline__ void gemm_async_body(
    const __hip_bfloat16* __restrict__ A, const __hip_bfloat16* __restrict__ W,
    const __hip_bfloat16* __restrict__ bias, void* __restrict__ C,
    int M, int N, int K, int bm, int bn, float outscale,
    __hip_bfloat16* smem)
{
    const int tid  = threadIdx.x;
    const int wave = tid >> 6;
    const int lane = tid & 63;
    const int quad = lane >> 4;
    const int l15  = lane & 15;
    const int wr   = wave >> 1;
    const int wc   = wave & 1;

    const int srow = wave * 16 + (lane >> 2);
    const int scol = (lane & 3) * 8;
    const __hip_bfloat16* gA0 = A + (size_t)(bm + srow) * K + scol;
    const __hip_bfloat16* gB0 = W + (size_t)(bn + srow) * K + scol;

    f32x4 acc[4][4];
#pragma unroll
    for (int i = 0; i < 4; i++)
#pragma unroll
        for (int j = 0; j < 4; j++) acc[i][j] = (f32x4)0.0f;

    // 4 global_load_lds(16B)/thread per tile
#define QSTAGE(buf, k0) { \
        __hip_bfloat16* d_ = smem + (buf) * 8192 + wave * 512; \
        async_copy16(gA0 + (k0), d_); \
        async_copy16(gA0 + (size_t)64 * K + (k0), d_ + 2048); \
        async_copy16(gB0 + (k0), d_ + 4096); \
        async_copy16(gB0 + (size_t)64 * K + (k0), d_ + 4096 + 2048); \
    }

    const int nt = K >> 5;
    QSTAGE(0, 0);
    for (int t = 0; t < nt; ++t) {
        const int buf = t & 1;
        const __hip_bfloat16* sA = smem + buf * 8192;
        const __hip_bfloat16* sB = sA + 4096;
        if (t + 1 < nt) {
            QSTAGE(1 - buf, (t + 1) * 32);
            asm volatile("s_waitcnt vmcnt(4)" ::: "memory");   // tile t's 4 loads done
        } else {
            asm volatile("s_waitcnt vmcnt(0)" ::: "memory");
        }
        __builtin_amdgcn_s_barrier();   // all waves staged tile t

        bf16x8 af[4], bf[4];
#pragma unroll
        for (int i = 0; i < 4; i++)
            af[i] = *(const bf16x8*)&sA[(wr * 64 + i * 16 + l15) * 32 + quad * 8];
#pragma unroll
        for (int j = 0; j < 4; j++)
            bf[j] = *(const bf16x8*)&sB[(wc * 64 + j * 16 + l15) * 32 + quad * 8];
#pragma unroll
        for (int i = 0; i < 4; i++)
#pragma unroll
            for (int j = 0; j < 4; j++)
                acc[i][j] = __builtin_amdgcn_mfma_f32_16x16x32_bf16(af[i], bf[j], acc[i][j], 0, 0, 0);

        __builtin_amdgcn_s_barrier();   // protect buf before overwrite at t+2
    }
#undef QSTAGE

    float bv[4];
#pragma unroll
    for (int j = 0; j < 4; j++)
        bv[j] = (float)bias[bn + wc * 64 + j * 16 + l15];

    if (MODE == 2) {
        // Stage tile as sOut[d_local][t_local] (stride 136), then write VT
        // coalesced (16B/lane, 256B contiguous per d-row).
        __hip_bfloat16* sOut = smem;
        __syncthreads();
#pragma unroll
        for (int i = 0; i < 4; i++) {
            int tl = wr * 64 + i * 16 + quad * 4;
#pragma unroll
            for (int j = 0; j < 4; j++) {
                int dl = wc * 64 + j * 16 + l15;
                union { __hip_bfloat16 e[4]; s16x4 v; } u;
#pragma unroll
                for (int r = 0; r < 4; r++)
                    u.e[r] = (__hip_bfloat16)(acc[i][j][r] + bv[j]);
                *(s16x4*)&sOut[dl * 136 + tl] = u.v;
            }
        }
        __syncthreads();
        __hip_bfloat16* VTo = (__hip_bfloat16*)C;
        const int bb = bm >> 11, tt0 = bm & 2047;
#pragma unroll
        for (int g8 = 0; g8 < 8; g8++) {
            int idx = g8 * 256 + tid;
            int dl  = idx >> 4;
            int tc  = (idx & 15) * 8;
            int dg  = bn + dl;
            bf16x8 v = *(const bf16x8*)&sOut[dl * 136 + tc];
            *(bf16x8*)&VTo[(((size_t)bb * 16 + (dg >> 6)) * 64 + (dg & 63)) * 2048 + tt0 + tc] = v;
        }
    } else {
#pragma unroll
        for (int i = 0; i < 4; i++) {
#pragma unroll
            for (int j = 0; j < 4; j++) {
                int col = bn + wc * 64 + j * 16 + l15;
#pragma unroll
                for (int r = 0; r < 4; r++) {
                    int row = bm + wr * 64 + i * 16 + quad * 4 + r;
                    float v = (acc[i][j][r] + bv[j]) * outscale;
                    if (MODE == 1) ((float*)C)[(size_t)row * N + col] = v;
                    else ((__hip_bfloat16*)C)[(size_t)row * N + col] = (__hip_bfloat16)v;
                }
            }
        }
    }
}

__global__ __launch_bounds__(256, 2) void qkv_gemm(
    const __hip_bfloat16* __restrict__ x,
    const __hip_bfloat16* __restrict__ Wq, const __hip_bfloat16* __restrict__ bq, __hip_bfloat16* __restrict__ Q,
    const __hip_bfloat16* __restrict__ Wk, const __hip_bfloat16* __restrict__ bk, __hip_bfloat16* __restrict__ Kb,
    const __hip_bfloat16* __restrict__ Wv, const __hip_bfloat16* __restrict__ bv, __hip_bfloat16* __restrict__ VT,
    int M, int N, int K)
{
    __shared__ __hip_bfloat16 smem[128 * 136];   // >= 2*8192 staging; sOut for MODE2
    if (blockIdx.z == 0)
        gemm_async_body<0>(x, Wq, bq, Q, M, N, K, blockIdx.x * 128, blockIdx.y * 128, QSCALE, smem);
    else if (blockIdx.z == 1)
        gemm_async_body<0>(x, Wk, bk, Kb, M, N, K, blockIdx.x * 128, blockIdx.y * 128, 1.0f, smem);
    else
        gemm_async_body<2>(x, Wv, bv, VT, M, N, K, blockIdx.x * 128, blockIdx.y * 128, 1.0f, smem);
}

// ---------------------------------------------------------------------------
// out_gemm 64x128, 2-phase prefetch. smem: [buf][sA 2048 | sB 4096] (24KB).
// ---------------------------------------------------------------------------
template <bool OF32>
__device__ __forceinline__ void gemm64_body(
    const __hip_bfloat16* __restrict__ A, const __hip_bfloat16* __restrict__ W,
    const __hip_bfloat16* __restrict__ bias, void* __restrict__ C,
    int M, int N, int K, int bm, int bn,
    __hip_bfloat16* smem)
{
    const int tid  = threadIdx.x;
    const int wave = tid >> 6;
    const int lane = tid & 63;
    const int quad = lane >> 4;
    const int l15  = lane & 15;

    const int srow = wave * 16 + (lane >> 2);
    const int scol = (lane & 3) * 8;
    const __hip_bfloat16* gA0 = A + (size_t)(bm + srow) * K + scol;
    const __hip_bfloat16* gB0 = W + (size_t)(bn + srow) * K + scol;

    f32x4 acc[4][2];
#pragma unroll
    for (int i = 0; i < 4; i++)
#pragma unroll
        for (int j = 0; j < 2; j++) acc[i][j] = (f32x4)0.0f;

    // 3 global_load_lds(16B)/thread per tile
#define OSTAGE(buf, k0) { \
        __hip_bfloat16* d_ = smem + (buf) * 6144; \
        async_copy16(gA0 + (k0), d_ + wave * 512); \
        async_copy16(gB0 + (k0), d_ + 2048 + wave * 512); \
        async_copy16(gB0 + (size_t)64 * K + (k0), d_ + 2048 + wave * 512 + 2048); \
    }

    const int nt = K >> 5;
    OSTAGE(0, 0);
    for (int t = 0; t < nt; ++t) {
        const int buf = t & 1;
        const __hip_bfloat16* sA = smem + buf * 6144;
        const __hip_bfloat16* sB = sA + 2048;
        if (t + 1 < nt) {
            OSTAGE(1 - buf, (t + 1) * 32);
            asm volatile("s_waitcnt vmcnt(3)" ::: "memory");   // tile t's 3 loads done
        } else {
            asm volatile("s_waitcnt vmcnt(0)" ::: "memory");
        }
        __builtin_amdgcn_s_barrier();

        bf16x8 af[4], bf[2];
#pragma unroll
        for (int i = 0; i < 4; i++)
            af[i] = *(const bf16x8*)&sA[(i * 16 + l15) * 32 + quad * 8];
#pragma unroll
        for (int j = 0; j < 2; j++)
            bf[j] = *(const bf16x8*)&sB[(wave * 32 + j * 16 + l15) * 32 + quad * 8];
#pragma unroll
        for (int i = 0; i < 4; i++)
#pragma unroll
            for (int j = 0; j < 2; j++)
                acc[i][j] = __builtin_amdgcn_mfma_f32_16x16x32_bf16(af[i], bf[j], acc[i][j], 0, 0, 0);

        __builtin_amdgcn_s_barrier();
    }
#undef OSTAGE

    float bv[2];
#pragma unroll
    for (int j = 0; j < 2; j++)
        bv[j] = (float)bias[bn + wave * 32 + j * 16 + l15];
#pragma unroll
    for (int i = 0; i < 4; i++) {
#pragma unroll
        for (int j = 0; j < 2; j++) {
            int col = bn + wave * 32 + j * 16 + l15;
#pragma unroll
            for (int r = 0; r < 4; r++) {
                int row = bm + i * 16 + quad * 4 + r;
                float v = acc[i][j][r] + bv[j];
                if (OF32) ((float*)C)[(size_t)row * N + col] = v;
                else      ((__hip_bfloat16*)C)[(size_t)row * N + col] = (__hip_bfloat16)v;
            }
        }
    }
}

__global__ __launch_bounds__(256, 2) void out_gemm(
    const __hip_bfloat16* __restrict__ A, const __hip_bfloat16* __restrict__ W,
    const __hip_bfloat16* __restrict__ bias, const void* __restrict__ origW,
    void* __restrict__ C, int M, int N, int K)
{
    __shared__ __hip_bfloat16 smem[2 * 6144];
    __shared__ int f32flag;
    if (threadIdx.x == 0) f32flag = sniff_f32(origW);
    __syncthreads();
    if (f32flag)
        gemm64_body<true>(A, W, bias, C, M, N, K, blockIdx.x * 64, blockIdx.y * 128, smem);
    else
        gemm64_body<false>(A, W, bias, C, M, N, K, blockIdx.x * 64, blockIdx.y * 128, smem);
}

// ---------------------------------------------------------------------------
// Flash attention, causal, no-max softmax, S^T formulation.  (R9 verbatim)
// 128-row q-tile, EIGHT waves x 16 q-rows. Double-buffered K/VT tiles,
// ONE barrier per iter. S^T = MFMA(A=K-rows, B=Q-rows): C col=l15=q,
// row=quad*4+r=key -> P values are 4 keys contiguous per (j): b64 sP writes.
// l is scalar/lane (q=l15); epilogue shuffles l to the C-layout rows.
// grid (16,16,2); qt = bz ? 15-bx : bx. 2 blocks/CU (104KB LDS) = 16 waves/CU.
// ---------------------------------------------------------------------------
#define PAD 68

__global__ __launch_bounds__(512, 4) void attn_causal(
    const __hip_bfloat16* __restrict__ Q,
    const __hip_bfloat16* __restrict__ K,
    const __hip_bfloat16* __restrict__ VT,
    __hip_bfloat16* __restrict__ O,
    int T, int D, int H)
{
    __shared__ __hip_bfloat16 sK[2][64 * PAD];
    __shared__ __hip_bfloat16 sVT[2][64 * PAD];
    __shared__ __hip_bfloat16 sPA[8][16 * PAD];   // per-wave P in A-layout

    const int tid  = threadIdx.x;
    const int wave = tid >> 6;      // 0..7
    const int lane = tid & 63;
    const int quad = lane >> 4;
    const int l15  = lane & 15;

    const int NT = T >> 7;  // 16 q-tiles of 128
    const int qt = blockIdx.z ? (NT - 1 - (int)blockIdx.x) : (int)blockIdx.x;
    const int h  = blockIdx.y;
    const int b  = blockIdx.z;
    const size_t headoff = (size_t)b * T * D + (size_t)h * 64;
    const size_t vtoff   = ((size_t)b * H + h) * 64 * (size_t)T;

    const int nkt = 2 * qt + 2;
    const int qbase    = qt * 128 + wave * 16;
    const int myrowmax = qbase + 15;

    // Q B-operand fragments in registers (block-lifetime constant)
    bf16x8 qfrag[2];
#pragma unroll
    for (int kk = 0; kk < 2; kk++)
        qfrag[kk] = *(const bf16x8*)&Q[headoff +
            (size_t)(qbase + l15) * D + kk * 32 + quad * 8];

    f32x4 acc_o[4];
#pragma unroll
    for (int j = 0; j < 4; j++) acc_o[j] = (f32x4)0.0f;
    float lacc = 0.f;   // per-lane l for q = qbase + l15 (partial over quads)

    const int srow = tid >> 3;        // 0..63: one 16B chunk per thread
    const int sc8  = (tid & 7) * 8;

    // pre-loop: stage kt=0 into buf0, prefetch kt=1
    bf16x8 pk, pv;
    pk = *(const bf16x8*)&K[headoff + (size_t)srow * D + sc8];
    pv = *(const bf16x8*)&VT[vtoff + (size_t)srow * T + sc8];
    *(bf16x8*)&sK[0][srow * PAD + sc8]  = pk;
    *(bf16x8*)&sVT[0][srow * PAD + sc8] = pv;
    if (nkt > 1) {
        pk = *(const bf16x8*)&K[headoff + (size_t)(64 + srow) * D + sc8];
        pv = *(const bf16x8*)&VT[vtoff + (size_t)srow * T + 64 + sc8];
    }
    __syncthreads();

    for (int kt = 0; kt < nkt; ++kt) {
        const int cur = kt & 1;

        // stage next tile into the other buffer (safe: barrier at end of kt-1
        // means all waves finished reading it in kt-1)
        if (kt + 1 < nkt) {
            *(bf16x8*)&sK[1 - cur][srow * PAD + sc8]  = pk;
            *(bf16x8*)&sVT[1 - cur][srow * PAD + sc8] = pv;
            if (kt + 2 < nkt) {
                pk = *(const bf16x8*)&K[headoff + (size_t)((kt + 2) * 64 + srow) * D + sc8];
                pv = *(const bf16x8*)&VT[vtoff + (size_t)srow * T + (kt + 2) * 64 + sc8];
            }
        }

        if (kt * 64 <= myrowmax) {
            // K/V fragments (A-operand = rows of K / rows of VT)
            bf16x8 kfrag[2][4], vfrag[2][4];
#pragma unroll
            for (int kk = 0; kk < 2; kk++)
#pragma unroll
                for (int j = 0; j < 4; j++) {
                    kfrag[kk][j] = *(const bf16x8*)&sK[cur][(j * 16 + l15) * PAD + kk * 32 + quad * 8];
                    vfrag[kk][j] = *(const bf16x8*)&sVT[cur][(j * 16 + l15) * PAD + kk * 32 + quad * 8];
                }

            f32x4 st[4];
#pragma unroll
            for (int j = 0; j < 4; j++) st[j] = (f32x4)0.0f;
            __builtin_amdgcn_s_setprio(1);
#pragma unroll
            for (int kk = 0; kk < 2; kk++)
#pragma unroll
                for (int j = 0; j < 4; j++)
                    st[j] = __builtin_amdgcn_mfma_f32_16x16x32_bf16(
                        kfrag[kk][j], qfrag[kk], st[j], 0, 0, 0);
            __builtin_amdgcn_s_setprio(0);

            if (kt * 64 + 63 > qbase) {   // wave-uniform mask check (diag tile)
                const int q = qbase + l15;
#pragma unroll
                for (int j = 0; j < 4; j++) {
                    int keyb = kt * 64 + j * 16 + quad * 4;
#pragma unroll
                    for (int r = 0; r < 4; r++)
                        if (keyb + r > q) st[j][r] = -1e30f;
                }
            }

#pragma unroll
            for (int j = 0; j < 4; j++) {
                union { __hip_bfloat16 e[4]; s16x4 v; } u;
#pragma unroll
                for (int r = 0; r < 4; r++) {
                    float p = exp2f(st[j][r]);
                    lacc += p;
                    u.e[r] = (__hip_bfloat16)p;
                }
                // 4 contiguous keys at row q=l15: one b64 write
                *(s16x4*)&sPA[wave][l15 * PAD + j * 16 + quad * 4] = u.v;
            }
            // sPA wave-local: lgkmcnt orders write->read, no barrier.
            __builtin_amdgcn_s_setprio(1);
#pragma unroll
            for (int kk = 0; kk < 2; kk++) {
                bf16x8 a = *(const bf16x8*)&sPA[wave][l15 * PAD + kk * 32 + quad * 8];
#pragma unroll
                for (int j = 0; j < 4; j++)
                    acc_o[j] = __builtin_amdgcn_mfma_f32_16x16x32_bf16(
                        a, vfrag[kk][j], acc_o[j], 0, 0, 0);
            }
            __builtin_amdgcn_s_setprio(0);
        }

        __syncthreads();   // single barrier per iter
    }

    // l lives per-lane for q=l15 (partial over quads): reduce across quads
    lacc += __shfl_xor(lacc, 16, 64);
    lacc += __shfl_xor(lacc, 32, 64);

    // acc_o rows are q = quad*4+r: fetch l from lane quad*4+r via shfl
#pragma unroll
    for (int r = 0; r < 4; r++) {
        float linv = 1.0f / __shfl(lacc, quad * 4 + r, 64);
        int row = qbase + quad * 4 + r;
#pragma unroll
        for (int j = 0; j < 4; j++) {
            int col = j * 16 + l15;
            O[headoff + (size_t)row * D + col] = (__hip_bfloat16)(acc_o[j][r] * linv);
        }
    }
}

// ---------------------------------------------------------------------------
extern "C" void kernel_launch(void* const* d_in, const int* in_sizes, int n_in,
                              void* d_out, int out_size, void* d_ws, size_t ws_size,
                              hipStream_t stream) {
    const int Bb = 2, T = 2048, D = 1024, H = 16;
    const int M = Bb * T;   // 4096

    __hip_bfloat16* w = (__hip_bfloat16*)d_ws;
    __hip_bfloat16* Q   = w;
    __hip_bfloat16* Kb  = Q   + (size_t)M * D;
    __hip_bfloat16* VT  = Kb  + (size_t)M * D;
    __hip_bfloat16* ctx = VT  + (size_t)M * D;
    __hip_bfloat16* xb  = ctx + (size_t)M * D;
    __hip_bfloat16* Wqb = xb  + (size_t)M * D;
    __hip_bfloat16* Wkb = Wqb + (size_t)D * D;
    __hip_bfloat16* Wvb = Wkb + (size_t)D * D;
    __hip_bfloat16* Wob = Wvb + (size_t)D * D;
    __hip_bfloat16* bqb = Wob + (size_t)D * D;
    __hip_bfloat16* bkb = bqb + D;
    __hip_bfloat16* bvb = bkb + D;
    __hip_bfloat16* bob = bvb + D;

    CvtPack pk;
    pk.a[0] = { d_in[0], xb,  M * D };
    pk.a[1] = { d_in[1], Wqb, D * D };
    pk.a[2] = { d_in[2], bqb, D };
    pk.a[3] = { d_in[3], Wkb, D * D };
    pk.a[4] = { d_in[4], bkb, D };
    pk.a[5] = { d_in[5], Wvb, D * D };
    pk.a[6] = { d_in[6], bvb, D };
    pk.a[7] = { d_in[7], Wob, D * D };
    pk.a[8] = { d_in[8], bob, D };

    cvt_bf16<<<dim3(512, 9), 256, 0, stream>>>(pk);
    qkv_gemm<<<dim3(M / 128, D / 128, 3), 256, 0, stream>>>(
        xb, Wqb, bqb, Q, Wkb, bkb, Kb, Wvb, bvb, VT, M, D, D);
    attn_causal<<<dim3(T / 128, H, Bb), 512, 0, stream>>>(Q, Kb, VT, ctx, T, D, H);
    out_gemm<<<dim3(M / 64, D / 128), 256, 0, stream>>>(
        ctx, Wob, bob, d_in[7], d_out, M, D, D);
}